// Round 1
// baseline (187.871 us; speedup 1.0000x reference)
//
#include <hip/hip_runtime.h>

// CRF log-partition forward, MI355X. 64 blocks (1 per sequence) x 256 threads
// (4 waves, pinned 1 wave/EU). Hybrid of R10 (4-wave quad-only combine) and
// R13 (f16 state + v_dot2_f32_f16):
//  - p stored in LDS as packed f16 pairs -> lane reads its 32-i chunk as
//    4x ds_read_b128 (16 wave-instr/step block-wide, half of R10)
//  - 32 fdot2 per lane (i-chunk 32 x j-pair {2g,2g+1}), 4 chains
//  - E tile only 32 h2 = 32 VGPRs: no AGPR parking (R13 lesson: big E tiles
//    get parked in AGPRs, VGPR_Count 132 cap, accvgpr shuttles on the chain)
//  - quad-only DPP combine (xor1+xor2), writer k==0 stores packed pair b32
//  - renormalizer: f16 exponent of OLD q0 (broadcast b32), folded into the
//    exp2 argument: q' = exp2(e*log2e - eS) * dot;  o += eS (exact)
//  - lgkmcnt-only barrier (R6 lesson: __syncthreads drains vmcnt and kills
//    the emission prefetch); distance-4 prefetch ring
// f16 q/E rounding validated: R13 ran f16 state end-to-end, absmax 0.0.
// Layout: pair-dword for tags {2g,2g+1} at (g>>4)*20 + (g&15); chunk k base
// k*20 dwords -> the 4 broadcast b128 addresses hit disjoint bank quads.

#define LOG2E 1.4426950408889634f
#define LN2   0.6931471805599453f

// LDS-only workgroup barrier: no vmcnt drain (cross-wave data is LDS only).
#define LDS_BARRIER() asm volatile("s_waitcnt lgkmcnt(0)\n\ts_barrier" ::: "memory")

typedef float    f2 __attribute__((ext_vector_type(2)));
typedef _Float16 h2 __attribute__((ext_vector_type(2)));

// cvt_pkrtz returns __fp16x2; bit_cast to h2 (_Float16x2), same 32 bits
#define PKRTZ(a, b) __builtin_bit_cast(h2, __builtin_amdgcn_cvt_pkrtz((a), (b)))

template <int CTRL>
__device__ __forceinline__ float dpp_f(float x) {
    return __int_as_float(
        __builtin_amdgcn_mov_dpp(__float_as_int(x), CTRL, 0xF, 0xF, false));
}
// quad_perm codes: xor1 = 0xB1, xor2 = 0x4E

__global__ __launch_bounds__(256)
__attribute__((amdgpu_waves_per_eu(1, 1)))
void crf_forward(
    const float* __restrict__ emissions,   // [64, 512, 128]
    const float* __restrict__ transitions, // [128, 128]
    const float* __restrict__ start_t,     // [128]
    const float* __restrict__ end_t,       // [128]
    const int*   __restrict__ lengths,     // [64]
    float* __restrict__ out)               // [64]
{
    constexpr int N = 128;
    constexpr int L = 512;
    const int b   = blockIdx.x;
    const int tid = threadIdx.x;
    const int g   = tid >> 2;   // tag pair {2g, 2g+1}, g in [0,64)
    const int k   = tid & 3;    // i-chunk: tags [32k, 32k+32) = pair-dwords [16k,16k+16)

    // f16-pair dwords; chunk k at padded base 20k (16B-aligned, disjoint banks)
    __shared__ alignas(16) float pbuf[2][80];
    __shared__ float wsum[4];

    // ---- one-time: E tile as 32 NAMED h2 registers (32 VGPRs).
    // EA_m = (E[32k+2m][2g], E[32k+2m+1][2g]); EB_m same for col 2g+1.
    h2 EA_0,  EA_1,  EA_2,  EA_3,  EA_4,  EA_5,  EA_6,  EA_7;
    h2 EA_8,  EA_9,  EA_10, EA_11, EA_12, EA_13, EA_14, EA_15;
    h2 EB_0,  EB_1,  EB_2,  EB_3,  EB_4,  EB_5,  EB_6,  EB_7;
    h2 EB_8,  EB_9,  EB_10, EB_11, EB_12, EB_13, EB_14, EB_15;
    {
        const float* tb = transitions + (size_t)(32 * k) * N + 2 * g;
#define INIT_M(m)                                                              \
        {                                                                      \
            f2 r0 = *reinterpret_cast<const f2*>(tb + (size_t)(2 * (m)) * N);  \
            f2 r1 = *reinterpret_cast<const f2*>(tb + (size_t)(2 * (m) + 1) * N); \
            EA_##m = PKRTZ(__builtin_amdgcn_exp2f(r0.x * LOG2E),               \
                           __builtin_amdgcn_exp2f(r1.x * LOG2E));              \
            EB_##m = PKRTZ(__builtin_amdgcn_exp2f(r0.y * LOG2E),               \
                           __builtin_amdgcn_exp2f(r1.y * LOG2E));              \
        }
        INIT_M(0)  INIT_M(1)  INIT_M(2)  INIT_M(3)
        INIT_M(4)  INIT_M(5)  INIT_M(6)  INIT_M(7)
        INIT_M(8)  INIT_M(9)  INIT_M(10) INIT_M(11)
        INIT_M(12) INIT_M(13) INIT_M(14) INIT_M(15)
#undef INIT_M
    }

    const int len = lengths[b];
    const float* eb = emissions + (size_t)b * L * N;

    // ---- init: raw q = exp(start + e0) for the lane's pair; k==0 writes
    int o = 0;
    int cur = 0;
    float qA, qB;
    {
        f2 st = *reinterpret_cast<const f2*>(start_t + 2 * g);
        f2 e0 = *reinterpret_cast<const f2*>(eb + 2 * g);
        qA = __builtin_amdgcn_exp2f((st.x + e0.x) * LOG2E);
        qB = __builtin_amdgcn_exp2f((st.y + e0.y) * LOG2E);
        if (k == 0)
            pbuf[0][(g >> 4) * 20 + (g & 15)] =
                __builtin_bit_cast(float, PKRTZ(qA, qB));
    }
    LDS_BARRIER();

    auto clampt = [&](int tt) { return tt < len ? tt : len - 1; };
    auto ldE = [&](int tt) {
        return *reinterpret_cast<const f2*>(eb + (size_t)tt * N + 2 * g);
    };

    auto STEP = [&](f2 ecur) {
        // old q0 (broadcast b32) + my 16 pair-dwords (4x b128, disjoint banks)
        float q0w = pbuf[cur][0];
        const float4* pv = reinterpret_cast<const float4*>(&pbuf[cur][k * 20]);
        float4 Q0 = pv[0], Q1 = pv[1], Q2 = pv[2], Q3 = pv[3];

        // eS = f16 exponent of old q0 (tag 0 = low half), bias 15
        unsigned u0 = __float_as_uint(q0w);
        int eS = (int)((u0 >> 10) & 0x1Fu) - 15;
        o += eS;
        float feS = (float)eS;
        float esA = __builtin_amdgcn_exp2f(ecur.x * LOG2E - feS);
        float esB = __builtin_amdgcn_exp2f(ecur.y * LOG2E - feS);

        // 32 v_dot2_f32_f16 over the 32i x 2j tile, 4 chains (depth 8)
        float aA0 = 0.f, aA1 = 0.f, aB0 = 0.f, aB1 = 0.f;
#define D0(m, Qc)                                                              \
        {                                                                      \
            h2 pm = __builtin_bit_cast(h2, Qc);                                \
            aA0 = __builtin_amdgcn_fdot2(pm, EA_##m, aA0, false);              \
            aB0 = __builtin_amdgcn_fdot2(pm, EB_##m, aB0, false);              \
        }
#define D1(m, Qc)                                                              \
        {                                                                      \
            h2 pm = __builtin_bit_cast(h2, Qc);                                \
            aA1 = __builtin_amdgcn_fdot2(pm, EA_##m, aA1, false);              \
            aB1 = __builtin_amdgcn_fdot2(pm, EB_##m, aB1, false);              \
        }
        D0(0,  Q0.x) D1(1,  Q0.y) D0(2,  Q0.z) D1(3,  Q0.w)
        D0(4,  Q1.x) D1(5,  Q1.y) D0(6,  Q1.z) D1(7,  Q1.w)
        D0(8,  Q2.x) D1(9,  Q2.y) D0(10, Q2.z) D1(11, Q2.w)
        D0(12, Q3.x) D1(13, Q3.y) D0(14, Q3.z) D1(15, Q3.w)
#undef D0
#undef D1
        float dA = aA0 + aA1;
        float dB = aB0 + aB1;

        // quad butterfly (DPP only): all 4 quad lanes get the full i-sum
        dA += dpp_f<0xB1>(dA); dB += dpp_f<0xB1>(dB);
        dA += dpp_f<0x4E>(dA); dB += dpp_f<0x4E>(dB);

        qA = esA * dA;
        qB = esB * dB;
        cur ^= 1;
        if (k == 0)
            pbuf[cur][(g >> 4) * 20 + (g & 15)] =
                __builtin_bit_cast(float, PKRTZ(qA, qB));
        LDS_BARRIER();
    };

    // ---- main loop: distance-4 emission prefetch, manual 4-way unroll
    f2 ra = ldE(clampt(1));
    f2 rb = ldE(clampt(2));
    f2 rc = ldE(clampt(3));
    f2 rd = ldE(clampt(4));

    int t = 1;
    while (t < len) {
        STEP(ra); ra = ldE(clampt(t + 4)); ++t; if (t >= len) break;
        STEP(rb); rb = ldE(clampt(t + 4)); ++t; if (t >= len) break;
        STEP(rc); rc = ldE(clampt(t + 4)); ++t; if (t >= len) break;
        STEP(rd); rd = ldE(clampt(t + 4)); ++t;
    }

    // ---- finalize: each quad holds its pair's q redundantly (x4) -> 0.25
    {
        f2 ef = *reinterpret_cast<const f2*>(end_t + 2 * g);
        float vend = qA * __builtin_amdgcn_exp2f(ef.x * LOG2E)
                   + qB * __builtin_amdgcn_exp2f(ef.y * LOG2E);
        vend *= 0.25f;
        #pragma unroll
        for (int m = 1; m < 64; m <<= 1) vend += __shfl_xor(vend, m);
        if ((tid & 63) == 0) wsum[tid >> 6] = vend;
    }
    LDS_BARRIER();
    if (tid == 0)
        out[b] = LN2 * ((float)o + __builtin_amdgcn_logf(
                     (wsum[0] + wsum[1]) + (wsum[2] + wsum[3])));
}

extern "C" void kernel_launch(void* const* d_in, const int* in_sizes, int n_in,
                              void* d_out, int out_size, void* d_ws, size_t ws_size,
                              hipStream_t stream) {
    const float* emissions   = (const float*)d_in[0];
    const float* transitions = (const float*)d_in[1];
    const float* start_t     = (const float*)d_in[2];
    const float* end_t       = (const float*)d_in[3];
    const int*   lengths     = (const int*)d_in[4];
    float* out = (float*)d_out;

    crf_forward<<<dim3(64), dim3(256), 0, stream>>>(
        emissions, transitions, start_t, end_t, lengths, out);
}

// Round 2
// 131.482 us; speedup vs baseline: 1.4289x; 1.4289x over previous
//
#include <hip/hip_runtime.h>

// CRF log-partition, MI355X — R2: bidirectional split (halve the serial depth).
// Wall time of the old kernel = len_max (~505) x per-step latency (~600 cyc),
// purely latency-bound (VALUBusy 4%, occupancy 1.4%, HBM 0.4%). Nothing about
// the step was the lever; the CHAIN LENGTH is. Z factors at any midpoint m:
//   Z = logsumexp_i( alpha_m[i] + beta_m[i] )
// alpha: forward from start+e_0 (includes e_m); beta: backward from end
// (covers e_{m+1}..e_{len-1}); both rank-1 at their ends, so both stay
// 128-vectors. Backward recurrence w_t = s~_t o (E * w_{t+1}) is the SAME
// step shape as forward (E row-indexed instead of column-indexed), so the
// validated STEP machinery is reused unchanged:
//  - f16-pair LDS state, 4x ds_read_b128 per lane, 32 fdot2 (4 chains)
//  - quad-only DPP combine (xor1+xor2), k==0 writes packed pair
//  - renorm: f16 exponent of state[0], folded into exp2 arg; o += eS exact
//  - lgkmcnt-only barrier; distance-4 emission prefetch ring
// Grid: 128 blocks (0..63 fwd seq b, 64..127 bwd seq b-64), concurrent.
// Then crf_combine (64 x 64): dot(alpha_m, x_m) + log + ln2*(oA+oB).
// Backward bookkeeping: m = (len-1)>>1. total = len-1-m backward steps:
//   init w_{len-1} = exp(e_{len-1}+end)   (if total>0; else output exp(end))
//   normal steps t = len-2 .. m+1 (count total-1), each: dot then scale by
//   s~_t = exp2(e_t*log2e - eS)
//   final step with ZERO emissions -> x_m = E*w_{m+1} (scaled 2^-eS, o+=eS)
// Every step multiplies by 2^-eS and adds eS to o, so value*2^o is exact.

#define LOG2E 1.4426950408889634f
#define LN2   0.6931471805599453f

// LDS-only workgroup barrier: no vmcnt drain (keeps emission prefetch alive).
#define LDS_BARRIER() asm volatile("s_waitcnt lgkmcnt(0)\n\ts_barrier" ::: "memory")

typedef float    f2 __attribute__((ext_vector_type(2)));
typedef _Float16 h2 __attribute__((ext_vector_type(2)));

#define PKRTZ(a, b) __builtin_bit_cast(h2, __builtin_amdgcn_cvt_pkrtz((a), (b)))

template <int CTRL>
__device__ __forceinline__ float dpp_f(float x) {
    return __int_as_float(
        __builtin_amdgcn_mov_dpp(__float_as_int(x), CTRL, 0xF, 0xF, false));
}
// quad_perm codes: xor1 = 0xB1, xor2 = 0x4E

__global__ __launch_bounds__(256)
__attribute__((amdgpu_waves_per_eu(1, 1)))
void crf_halves(
    const float* __restrict__ emissions,   // [64, 512, 128]
    const float* __restrict__ transitions, // [128, 128]
    const float* __restrict__ start_t,     // [128]
    const float* __restrict__ end_t,       // [128]
    const int*   __restrict__ lengths,     // [64]
    float* __restrict__ wsV,               // [2][64][128] half-vectors
    int*   __restrict__ wsO)               // [2][64] exponent accumulators
{
    constexpr int N = 128;
    constexpr int L = 512;
    const int  bid = blockIdx.x;
    const bool isf = bid < 64;        // forward half?
    const int  b   = isf ? bid : bid - 64;
    const int  tid = threadIdx.x;
    const int  g   = tid >> 2;        // tag pair {2g, 2g+1}
    const int  k   = tid & 3;         // chunk: tags [32k, 32k+32)

    __shared__ alignas(16) float pbuf[2][80];

    // ---- E tile: 32 named h2 regs. fwd: EA_m=(E[32k+2m][2g],E[32k+2m+1][2g])
    // (column-indexed, as before). bwd: EA_m=(E[2g][32k+2m],E[2g][32k+2m+1])
    // (row-indexed = transposed tile), EB from row 2g+1.
    h2 EA_0,  EA_1,  EA_2,  EA_3,  EA_4,  EA_5,  EA_6,  EA_7;
    h2 EA_8,  EA_9,  EA_10, EA_11, EA_12, EA_13, EA_14, EA_15;
    h2 EB_0,  EB_1,  EB_2,  EB_3,  EB_4,  EB_5,  EB_6,  EB_7;
    h2 EB_8,  EB_9,  EB_10, EB_11, EB_12, EB_13, EB_14, EB_15;
    if (isf) {
        const float* tb = transitions + (size_t)(32 * k) * N + 2 * g;
#define INIT_F(m)                                                              \
        {                                                                      \
            f2 r0 = *reinterpret_cast<const f2*>(tb + (size_t)(2 * (m)) * N);  \
            f2 r1 = *reinterpret_cast<const f2*>(tb + (size_t)(2 * (m) + 1) * N); \
            EA_##m = PKRTZ(__builtin_amdgcn_exp2f(r0.x * LOG2E),               \
                           __builtin_amdgcn_exp2f(r1.x * LOG2E));              \
            EB_##m = PKRTZ(__builtin_amdgcn_exp2f(r0.y * LOG2E),               \
                           __builtin_amdgcn_exp2f(r1.y * LOG2E));              \
        }
        INIT_F(0)  INIT_F(1)  INIT_F(2)  INIT_F(3)
        INIT_F(4)  INIT_F(5)  INIT_F(6)  INIT_F(7)
        INIT_F(8)  INIT_F(9)  INIT_F(10) INIT_F(11)
        INIT_F(12) INIT_F(13) INIT_F(14) INIT_F(15)
#undef INIT_F
    } else {
        const float* ra_ = transitions + (size_t)(2 * g) * N + 32 * k;
        const float* rb_ = transitions + (size_t)(2 * g + 1) * N + 32 * k;
#define INIT_B(m)                                                              \
        {                                                                      \
            f2 r0 = *reinterpret_cast<const f2*>(ra_ + 2 * (m));               \
            f2 r1 = *reinterpret_cast<const f2*>(rb_ + 2 * (m));               \
            EA_##m = PKRTZ(__builtin_amdgcn_exp2f(r0.x * LOG2E),               \
                           __builtin_amdgcn_exp2f(r0.y * LOG2E));              \
            EB_##m = PKRTZ(__builtin_amdgcn_exp2f(r1.x * LOG2E),               \
                           __builtin_amdgcn_exp2f(r1.y * LOG2E));              \
        }
        INIT_B(0)  INIT_B(1)  INIT_B(2)  INIT_B(3)
        INIT_B(4)  INIT_B(5)  INIT_B(6)  INIT_B(7)
        INIT_B(8)  INIT_B(9)  INIT_B(10) INIT_B(11)
        INIT_B(12) INIT_B(13) INIT_B(14) INIT_B(15)
#undef INIT_B
    }

    const int len = lengths[b];
    const int m   = (len - 1) >> 1;
    const float* eb = emissions + (size_t)b * L * N;

    // step schedule
    int n_steps, e0, dstep; bool zfinal;
    if (isf) {
        n_steps = m; e0 = 1; dstep = 1; zfinal = false;
    } else {
        int total = len - 1 - m;
        n_steps = total > 0 ? total - 1 : 0;
        e0 = len - 2; if (e0 < 0) e0 = 0;
        dstep = -1;
        zfinal = total > 0;
    }

    // ---- init state
    int o = 0, cur = 0;
    float qA, qB;
    {
        const float* base = isf ? start_t : end_t;
        f2 bt = *reinterpret_cast<const f2*>(base + 2 * g);
        f2 ev;
        if (isf)         ev = *reinterpret_cast<const f2*>(eb + 2 * g);
        else if (zfinal) ev = *reinterpret_cast<const f2*>(eb + (size_t)(len - 1) * N + 2 * g);
        else           { ev.x = 0.f; ev.y = 0.f; }
        qA = __builtin_amdgcn_exp2f((bt.x + ev.x) * LOG2E);
        qB = __builtin_amdgcn_exp2f((bt.y + ev.y) * LOG2E);
        if (k == 0)
            pbuf[0][(g >> 4) * 20 + (g & 15)] =
                __builtin_bit_cast(float, PKRTZ(qA, qB));
    }
    LDS_BARRIER();

    auto eidx = [&](int n) {
        int nn = (n < n_steps) ? n : (n_steps - 1);
        if (nn < 0) nn = 0;
        return e0 + dstep * nn;
    };
    auto ldE = [&](int tt) {
        return *reinterpret_cast<const f2*>(eb + (size_t)tt * N + 2 * g);
    };

    auto STEP = [&](f2 ecur) {
        float q0w = pbuf[cur][0];
        const float4* pv = reinterpret_cast<const float4*>(&pbuf[cur][k * 20]);
        float4 Q0 = pv[0], Q1 = pv[1], Q2 = pv[2], Q3 = pv[3];

        unsigned u0 = __float_as_uint(q0w);
        int eS = (int)((u0 >> 10) & 0x1Fu) - 15;
        o += eS;
        float feS = (float)eS;
        float esA = __builtin_amdgcn_exp2f(ecur.x * LOG2E - feS);
        float esB = __builtin_amdgcn_exp2f(ecur.y * LOG2E - feS);

        float aA0 = 0.f, aA1 = 0.f, aB0 = 0.f, aB1 = 0.f;
#define D0(m_, Qc)                                                             \
        {                                                                      \
            h2 pm = __builtin_bit_cast(h2, Qc);                                \
            aA0 = __builtin_amdgcn_fdot2(pm, EA_##m_, aA0, false);             \
            aB0 = __builtin_amdgcn_fdot2(pm, EB_##m_, aB0, false);             \
        }
#define D1(m_, Qc)                                                             \
        {                                                                      \
            h2 pm = __builtin_bit_cast(h2, Qc);                                \
            aA1 = __builtin_amdgcn_fdot2(pm, EA_##m_, aA1, false);             \
            aB1 = __builtin_amdgcn_fdot2(pm, EB_##m_, aB1, false);             \
        }
        D0(0,  Q0.x) D1(1,  Q0.y) D0(2,  Q0.z) D1(3,  Q0.w)
        D0(4,  Q1.x) D1(5,  Q1.y) D0(6,  Q1.z) D1(7,  Q1.w)
        D0(8,  Q2.x) D1(9,  Q2.y) D0(10, Q2.z) D1(11, Q2.w)
        D0(12, Q3.x) D1(13, Q3.y) D0(14, Q3.z) D1(15, Q3.w)
#undef D0
#undef D1
        float dA = aA0 + aA1;
        float dB = aB0 + aB1;

        dA += dpp_f<0xB1>(dA); dB += dpp_f<0xB1>(dB);
        dA += dpp_f<0x4E>(dA); dB += dpp_f<0x4E>(dB);

        qA = esA * dA;
        qB = esB * dB;
        cur ^= 1;
        if (k == 0)
            pbuf[cur][(g >> 4) * 20 + (g & 15)] =
                __builtin_bit_cast(float, PKRTZ(qA, qB));
        LDS_BARRIER();
    };

    // ---- main loop: distance-4 prefetch ring, 4-way unroll
    f2 ra = ldE(eidx(0));
    f2 rb = ldE(eidx(1));
    f2 rc = ldE(eidx(2));
    f2 rd = ldE(eidx(3));

    int n = 0;
    while (n < n_steps) {
        STEP(ra); ra = ldE(eidx(n + 4)); ++n; if (n >= n_steps) break;
        STEP(rb); rb = ldE(eidx(n + 4)); ++n; if (n >= n_steps) break;
        STEP(rc); rc = ldE(eidx(n + 4)); ++n; if (n >= n_steps) break;
        STEP(rd); rd = ldE(eidx(n + 4)); ++n;
    }
    if (zfinal) {              // x_m = E * w_{m+1}: zero-emission step
        f2 z; z.x = 0.f; z.y = 0.f;
        STEP(z);
    }

    // ---- write half-result: f32 pair + exponent accumulator
    float* wv = wsV + (size_t)((isf ? 0 : 64) + b) * 128;
    if (k == 0) {
        f2 q; q.x = qA; q.y = qB;
        *reinterpret_cast<f2*>(wv + 2 * g) = q;
    }
    if (tid == 0) wsO[(isf ? 0 : 64) + b] = o;
}

__global__ __launch_bounds__(64)
void crf_combine(const float* __restrict__ wsV, const int* __restrict__ wsO,
                 const int* __restrict__ lengths, float* __restrict__ out)
{
    const int b = blockIdx.x;
    const int g = threadIdx.x;   // 64 lanes, pair {2g,2g+1}
    f2 a = *reinterpret_cast<const f2*>(wsV + (size_t)b * 128 + 2 * g);
    f2 x = *reinterpret_cast<const f2*>(wsV + (size_t)(64 + b) * 128 + 2 * g);
    float v = a.x * x.x + a.y * x.y;
    #pragma unroll
    for (int s = 1; s < 64; s <<= 1) v += __shfl_xor(v, s);
    if (g == 0)
        out[b] = LN2 * ((float)(wsO[b] + wsO[64 + b]) +
                        __builtin_amdgcn_logf(v));
}

extern "C" void kernel_launch(void* const* d_in, const int* in_sizes, int n_in,
                              void* d_out, int out_size, void* d_ws, size_t ws_size,
                              hipStream_t stream) {
    const float* emissions   = (const float*)d_in[0];
    const float* transitions = (const float*)d_in[1];
    const float* start_t     = (const float*)d_in[2];
    const float* end_t       = (const float*)d_in[3];
    const int*   lengths     = (const int*)d_in[4];
    float* out = (float*)d_out;

    float* wsV = (float*)d_ws;                                   // [2][64][128]
    int*   wsO = (int*)((char*)d_ws + 2 * 64 * 128 * sizeof(float)); // [2][64]

    crf_halves<<<dim3(128), dim3(256), 0, stream>>>(
        emissions, transitions, start_t, end_t, lengths, wsV, wsO);
    crf_combine<<<dim3(64), dim3(64), 0, stream>>>(wsV, wsO, lengths, out);
}